// Round 7
// baseline (378.881 us; speedup 1.0000x reference)
//
#include <hip/hip_runtime.h>

#define N_TOK 65536
#define D 64
#define C_CODES 2048
#define DECAYF 0.8f
#define OMDF 0.2f
#define EPSF 1e-5f
#define SEG 16           // sorted positions per wave in seg_sum
#define GAP_THR 0.03125f // > 2x the worst-case split-bf16 screen error (~0.012)
#define TCODES 64        // codes per staged LDS tile
#define HT (1024 / TCODES)  // 16 tiles per codebook half

// output layout (floats), concatenated in reference return order
#define OUT_QUANT 0
#define OUT_IND   (N_TOK * D)               // 4194304
#define OUT_EMB   (OUT_IND + N_TOK)         // 4259840
#define OUT_CS    (OUT_EMB + C_CODES * D)   // 4390912
#define OUT_EAVG  (OUT_CS + C_CODES)        // 4392960

typedef short s16x8 __attribute__((ext_vector_type(8)));  // 8 bf16 (4 VGPRs)
typedef float f32x4 __attribute__((ext_vector_type(4)));

__device__ __forceinline__ unsigned short f2bf(float f) {  // RNE float->bf16 bits
    unsigned int u = __float_as_uint(f);
    return (unsigned short)((u + 0x7fffu + ((u >> 16) & 1u)) >> 16);
}
__device__ __forceinline__ float bf2f(unsigned short h) {
    return __uint_as_float(((unsigned int)h) << 16);
}
__device__ __forceinline__ unsigned long long shflx64w(unsigned long long v, int mask, int w) {
    unsigned int lo = (unsigned int)v, hi = (unsigned int)(v >> 32);
    lo = __shfl_xor(lo, mask, w);
    hi = __shfl_xor(hi, mask, w);
    return ((unsigned long long)hi << 32) | lo;
}
__device__ __forceinline__ void gload_lds16(const void* g, void* l) {
    __builtin_amdgcn_global_load_lds(
        (const __attribute__((address_space(1))) void*)g,
        (__attribute__((address_space(3))) void*)l, 16, 0, 0);
}

// Codebook prep: hi/lo bf16 split, PRE-SWIZZLED rows (slot s holds k-chunk
// s^(code&7)) so linear global_load_lds staging + swizzled ds_read_b128 is
// conflict-free. Threads g<2048 also compute e2 with the VERBATIM validated
// fmaf tree (order is load-bearing for near-tie argmin bits) + bf16-pair e2p.
// Also zeroes counts and embed_sum (no memset dispatches).
__global__ void eprep_kernel(const float* __restrict__ emb, short* __restrict__ ebk,
                             float* __restrict__ e2, unsigned int* __restrict__ e2p,
                             float* __restrict__ counts, float* __restrict__ embed_sum) {
    int g = blockIdx.x * blockDim.x + threadIdx.x;  // [0, C_CODES*8)
    int code = g >> 3, slot = g & 7;
    int kc = slot ^ (code & 7);
    const float4* ep = (const float4*)(emb + (size_t)code * D + kc * 8);
    float4 a = ep[0], b = ep[1];
    float v[8] = {a.x, a.y, a.z, a.w, b.x, b.y, b.z, b.w};
    s16x8 h, l;
#pragma unroll
    for (int j = 0; j < 8; ++j) {
        unsigned short hb = f2bf(v[j]);
        h[j] = (short)hb;
        l[j] = (short)f2bf(v[j] - bf2f(hb));
    }
    *(s16x8*)(ebk + (size_t)code * 128 + slot * 8) = h;
    *(s16x8*)(ebk + (size_t)code * 128 + 64 + slot * 8) = l;

    float4 z = {0.f, 0.f, 0.f, 0.f};
    ((float4*)embed_sum)[g * 2] = z;
    ((float4*)embed_sum)[g * 2 + 1] = z;
    if (g < C_CODES / 4) ((float4*)counts)[g] = z;

    if (g < C_CODES) {  // verbatim e2 tree
        const float4* er = (const float4*)(emb + (size_t)g * D);
        float s0 = 0.f, s1 = 0.f, s2 = 0.f, s3 = 0.f;
#pragma unroll
        for (int i = 0; i < D / 4; ++i) {
            float4 e = er[i];
            s0 = fmaf(e.x, e.x, s0);
            s1 = fmaf(e.y, e.y, s1);
            s2 = fmaf(e.z, e.z, s2);
            s3 = fmaf(e.w, e.w, s3);
        }
        float vv = (s0 + s1) + (s2 + s3);
        e2[g] = vv;
        unsigned short hb = f2bf(vv);
        unsigned short lb = f2bf(vv - bf2f(hb));
        e2p[g] = (unsigned int)hb | ((unsigned int)lb << 16);
    }
}

// MFMA screening over HALF the codebook per block (blockIdx.y). Branchless
// TOP-2 tracking (fmed3 second-min trick, no c2): 5 VALU/score. Emits per
// half one uint4 {b1_bits, c1, b2_bits, 0} per token. exact_kernel merges
// halves; gap12 > THR -> provably the reference argmin; else full coop scan.
__global__ __launch_bounds__(256) void screen_kernel(
        const float* __restrict__ x, const short* __restrict__ ebk,
        const unsigned int* __restrict__ e2p, uint4* __restrict__ ktop2) {
    __shared__ unsigned int e2pl[1024];                     // 4 KB (this half)
    __shared__ __align__(16) char bstage[2][TCODES * 256];  // 2 x 16 KB

    const int tid = threadIdx.x;
    const int bh = blockIdx.y;  // codebook half (0/1)
    if (tid < 256) ((uint4*)e2pl)[tid] = ((const uint4*)(e2p + bh * 1024))[tid];

    const int lane = tid & 63;
    const int wave = tid >> 6;
    const int col = lane & 15;   // B col / C col (code within subtile)
    const int krow = lane >> 4;  // k-group

    // A fragments: 2 sets of 16 tokens; split (-2*x) to bf16 hi/lo in-reg.
    s16x8 ah[2][2], al[2][2];
#pragma unroll
    for (int s = 0; s < 2; ++s) {
        int tok = blockIdx.x * 128 + wave * 32 + s * 16 + col;
        const float4* xp = (const float4*)(x + (size_t)tok * D + krow * 8);
        float4 f0 = xp[0], f1 = xp[1], f2 = xp[8], f3 = xp[9];
        float xv[16] = {f0.x, f0.y, f0.z, f0.w, f1.x, f1.y, f1.z, f1.w,
                        f2.x, f2.y, f2.z, f2.w, f3.x, f3.y, f3.z, f3.w};
#pragma unroll
        for (int j = 0; j < 8; ++j) {
            float v0 = -2.0f * xv[j];
            unsigned short h0 = f2bf(v0);
            ah[s][0][j] = (short)h0;
            al[s][0][j] = (short)f2bf(v0 - bf2f(h0));
            float v1 = -2.0f * xv[8 + j];
            unsigned short h1 = f2bf(v1);
            ah[s][1][j] = (short)h1;
            al[s][1][j] = (short)f2bf(v1 - bf2f(h1));
        }
    }

    // constant-A operand for the e2 fold: rows all 1.0 at k-slots 0,1.
    s16x8 aone = {0, 0, 0, 0, 0, 0, 0, 0};
    {
        short o = (krow == 0) ? (short)0x3F80 : (short)0;
        aone[0] = o;
        aone[1] = o;
    }
    const f32x4 zero = {0.f, 0.f, 0.f, 0.f};

    // top-2 state
    float b1[2][4], b2[2][4];
    unsigned int c1[2][4];
#pragma unroll
    for (int s = 0; s < 2; ++s)
#pragma unroll
        for (int r = 0; r < 4; ++r) {
            b1[s][r] = __builtin_inff();
            b2[s][r] = __builtin_inff();
            c1[s][r] = 0u;
        }

    // stage one 64-code tile (16 KB): 4 waves x 4 x global_load_lds(16B)
    auto stage = [&](int b, int t) {
        const char* src = (const char*)ebk + (size_t)(bh * HT + t) * (TCODES * 256)
                          + wave * 4096 + lane * 16;
        char* dst = &bstage[b][wave * 4096];
        gload_lds16(src, dst);
        gload_lds16(src + 1024, dst + 1024);
        gload_lds16(src + 2048, dst + 2048);
        gload_lds16(src + 3072, dst + 3072);
    };

    // one 16-code subtile: 4 ds_read_b128 + e2-fold MFMA + 12 chained MFMA +
    // top-2 update (5 VALU/score)
    auto subtile = [&](const char* lb, int t, int j) {
        const char* base = lb + (j << 12) + (col << 8);
        int off = (krow ^ (col & 7)) << 4;
        s16x8 bh0 = *(const s16x8*)(base + off);
        s16x8 bh1 = *(const s16x8*)(base + (off ^ 64));
        s16x8 bl0 = *(const s16x8*)(base + 128 + off);
        s16x8 bl1 = *(const s16x8*)(base + 128 + (off ^ 64));
        int sloc = t * 4 + j;  // subtile index within half
        unsigned int cg = (unsigned int)(bh * 1024 + sloc * 16 + col);
        unsigned int v = e2pl[sloc * 16 + col];
        v = (krow == 0) ? v : 0u;
        s16x8 be2 = {(short)(v & 0xffffu), (short)(v >> 16), 0, 0, 0, 0, 0, 0};
        f32x4 f = __builtin_amdgcn_mfma_f32_16x16x32_bf16(aone, be2, zero, 0, 0, 0);
#pragma unroll
        for (int s = 0; s < 2; ++s) {
            f32x4 a0 = __builtin_amdgcn_mfma_f32_16x16x32_bf16(ah[s][1], bh1, f, 0, 0, 0);
            a0 = __builtin_amdgcn_mfma_f32_16x16x32_bf16(ah[s][0], bh0, a0, 0, 0, 0);
            a0 = __builtin_amdgcn_mfma_f32_16x16x32_bf16(al[s][1], bh1, a0, 0, 0, 0);
            f32x4 a1 = __builtin_amdgcn_mfma_f32_16x16x32_bf16(al[s][0], bh0, zero, 0, 0, 0);
            a1 = __builtin_amdgcn_mfma_f32_16x16x32_bf16(ah[s][1], bl1, a1, 0, 0, 0);
            a1 = __builtin_amdgcn_mfma_f32_16x16x32_bf16(ah[s][0], bl0, a1, 0, 0, 0);
#pragma unroll
            for (int r = 0; r < 4; ++r) {
                float sc = a0[r] + a1[r];
                bool l1 = sc < b1[s][r];
                b2[s][r] = __builtin_amdgcn_fmed3f(b1[s][r], b2[s][r], sc);
                b1[s][r] = fminf(b1[s][r], sc);
                c1[s][r] = l1 ? cg : c1[s][r];
            }
        }
    };

    stage(0, 0);
    __syncthreads();  // drains staging + e2pl init

    for (int t = 0; t < HT; ++t) {
        if (t + 1 < HT) stage((t + 1) & 1, t + 1);
        const char* lb = bstage[t & 1];
        subtile(lb, t, 0);
        subtile(lb, t, 1);
        subtile(lb, t, 2);
        subtile(lb, t, 3);
        __syncthreads();
    }

    // cross-lane (16 cols) top-2 merge, then emit this half's result
#pragma unroll
    for (int s = 0; s < 2; ++s)
#pragma unroll
        for (int r = 0; r < 4; ++r) {
            float B1 = b1[s][r], B2 = b2[s][r];
            unsigned int C1 = c1[s][r];
#pragma unroll
            for (int mk = 1; mk < 16; mk <<= 1) {
                float o1 = __shfl_xor(B1, mk, 16);
                float o2 = __shfl_xor(B2, mk, 16);
                unsigned int oc = (unsigned int)__shfl_xor((int)C1, mk, 16);
                float hi = fmaxf(B1, o1);
                B2 = fminf(fminf(B2, o2), hi);
                bool take = o1 < B1;
                B1 = fminf(B1, o1);
                C1 = take ? oc : C1;
            }
            if (col == 0) {
                int tok = blockIdx.x * 128 + wave * 32 + s * 16 + krow * 4 + r;
                uint4 o;
                o.x = __float_as_uint(B1);
                o.y = C1;
                o.z = __float_as_uint(B2);
                o.w = 0u;
                ktop2[(size_t)tok * 2 + bh] = o;
            }
        }
}

// Merge both halves' top-2; gap12 > THR -> copy the provable argmin; else
// WAVE-COOPERATIVE full exact scan (VERBATIM expression tree, key-min:
// bits<<32|c -> ties pick smaller c). Fused quantize gather + histogram.
__global__ __launch_bounds__(256) void exact_kernel(
        const float* __restrict__ x, const float* __restrict__ emb,
        const float* __restrict__ e2, const uint4* __restrict__ ktop2,
        int* __restrict__ idx, float* __restrict__ out,
        float* __restrict__ counts) {
    __shared__ float lcount[C_CODES];
    for (int i = threadIdx.x; i < C_CODES; i += blockDim.x) lcount[i] = 0.0f;
    __syncthreads();
    int n = blockIdx.x * blockDim.x + threadIdx.x;
    int lane = threadIdx.x & 63;

    uint4 A = ktop2[(size_t)n * 2];
    uint4 B = ktop2[(size_t)n * 2 + 1];
    float a1 = __uint_as_float(A.x), a2 = __uint_as_float(A.z);
    float b1f = __uint_as_float(B.x), b2f = __uint_as_float(B.z);
    bool ta = a1 <= b1f;
    float m1 = ta ? a1 : b1f;
    int c = (int)(ta ? A.y : B.y);
    float m2 = fminf(fminf(a2, b2f), ta ? b1f : a1);
    bool fullf = !(m2 - m1 > GAP_THR);

    // cooperative exact scan for flagged lanes (chunked x reloads: no big
    // live ranges -> no scratch; x-row addrs wave-uniform -> broadcast)
    unsigned long long bal = __ballot(fullf);
    while (bal) {
        int src = (int)__ffsll((long long)bal) - 1;
        bal &= bal - 1;
        int tn = (n & ~63) + src;
        float xs[4] = {0.f, 0.f, 0.f, 0.f};
        for (int q = 0; q < 4; ++q) {
            const float4* xq = (const float4*)(x + (size_t)tn * D + q * 16);
#pragma unroll
            for (int j = 0; j < 4; ++j) {
                float4 xv = xq[j];
                xs[0] = fmaf(xv.x, xv.x, xs[0]);
                xs[1] = fmaf(xv.y, xv.y, xs[1]);
                xs[2] = fmaf(xv.z, xv.z, xs[2]);
                xs[3] = fmaf(xv.w, xv.w, xs[3]);
            }
        }
        float tx2 = (xs[0] + xs[1]) + (xs[2] + xs[3]);
        unsigned long long kbest = ~0ull;
        for (int cc = lane; cc < C_CODES; cc += 64) {
            float d0 = 0.f, d1 = 0.f, d2 = 0.f, d3 = 0.f;
            for (int q = 0; q < 4; ++q) {
                const float4* xq = (const float4*)(x + (size_t)tn * D + q * 16);
                const float4* er = (const float4*)(emb + (size_t)cc * D + q * 16);
#pragma unroll
                for (int j = 0; j < 4; ++j) {
                    float4 xv = xq[j], ev = er[j];
                    d0 = fmaf(xv.x, ev.x, d0);
                    d1 = fmaf(xv.y, ev.y, d1);
                    d2 = fmaf(xv.z, ev.z, d2);
                    d3 = fmaf(xv.w, ev.w, d3);
                }
            }
            float dot = (d0 + d1) + (d2 + d3);
            float dist2 = fmaxf(tx2 + e2[cc] - 2.0f * dot, 0.0f);
            unsigned long long key =
                ((unsigned long long)__float_as_uint(dist2) << 32) | (unsigned int)cc;
            kbest = key < kbest ? key : kbest;
        }
#pragma unroll
        for (int mk = 1; mk < 64; mk <<= 1) {
            unsigned long long o = shflx64w(kbest, mk, 64);
            kbest = o < kbest ? o : kbest;
        }
        if (lane == src) c = (int)(kbest & 0xffffffffull);
    }

    idx[n] = c;
    out[OUT_IND + n] = (float)c;
    atomicAdd(&lcount[c], 1.0f);

    // fused quantize gather: copy code row (codebook is L2-resident)
    {
        const float4* er = (const float4*)(emb + (size_t)c * D);
        float4* qo = (float4*)(out + OUT_QUANT) + (size_t)n * 16;
#pragma unroll
        for (int q = 0; q < 4; ++q) {
            float4 t0 = er[q * 4], t1 = er[q * 4 + 1], t2 = er[q * 4 + 2], t3 = er[q * 4 + 3];
            qo[q * 4] = t0;
            qo[q * 4 + 1] = t1;
            qo[q * 4 + 2] = t2;
            qo[q * 4 + 3] = t3;
        }
    }

    __syncthreads();
    for (int i = threadIdx.x; i < C_CODES; i += blockDim.x) {
        float vv = lcount[i];
        if (vv != 0.0f) atomicAdd(&counts[i], vv);
    }
}

// Single block: EMA cluster-size + laplace smoothing + exclusive prefix sum.
__global__ void prefix_ema_kernel(const float* __restrict__ counts,
                                  const float* __restrict__ cluster_size,
                                  float* __restrict__ out,
                                  float* __restrict__ smoothed,
                                  int* __restrict__ cursor) {
    __shared__ float scan[256];
    __shared__ float red[256];
    int t = threadIdx.x;
    int base = t * 8;
    float cnt[8], ncs[8];
    float csum = 0.f, nsum = 0.f;
#pragma unroll
    for (int j = 0; j < 8; ++j) {
        cnt[j] = counts[base + j];
        csum += cnt[j];
        ncs[j] = cluster_size[base + j] * DECAYF + cnt[j] * OMDF;
        nsum += ncs[j];
        out[OUT_CS + base + j] = ncs[j];
    }
    scan[t] = csum;
    red[t] = nsum;
    __syncthreads();
    for (int s = 1; s < 256; s <<= 1) {
        float v = scan[t];
        float w = (t >= s) ? scan[t - s] : 0.f;
        __syncthreads();
        scan[t] = v + w;
        __syncthreads();
    }
    for (int s = 128; s > 0; s >>= 1) {
        if (t < s) red[t] += red[t + s];
        __syncthreads();
    }
    float tot = red[0];
    float run = (t == 0) ? 0.f : scan[t - 1];
#pragma unroll
    for (int j = 0; j < 8; ++j) {
        cursor[base + j] = (int)run;  // counts are small ints in float: exact
        run += cnt[j];
        smoothed[base + j] = (ncs[j] + EPSF) / (tot + (float)C_CODES * EPSF) * tot;
    }
}

// counting-sort position scatter; entry packs (code<<16 | token).
__global__ void scatter_pos_kernel(const int* __restrict__ idx,
                                   int* __restrict__ cursor,
                                   unsigned int* __restrict__ sorted) {
    int n = blockIdx.x * blockDim.x + threadIdx.x;
    int c = idx[n];
    int pos = atomicAdd(&cursor[c], 1);
    sorted[pos] = ((unsigned int)c << 16) | (unsigned int)n;
}

// Segmented sum over sorted positions: one 64-lane atomicAdd per run boundary.
__global__ __launch_bounds__(256) void seg_sum_kernel(
        const float* __restrict__ x, const unsigned int* __restrict__ sorted,
        float* __restrict__ embed_sum) {
    int lane = threadIdx.x & 63;
    int q = blockIdx.x * 4 + (threadIdx.x >> 6);  // wave id
    int p0 = q * SEG;

    unsigned int mine = (lane < SEG) ? sorted[p0 + lane] : 0u;
    unsigned int pk[SEG];
#pragma unroll
    for (int j = 0; j < SEG; ++j) pk[j] = __shfl(mine, j, 64);

    float xv[SEG];
#pragma unroll
    for (int j = 0; j < SEG; ++j)
        xv[j] = x[(size_t)(pk[j] & 0xffffu) * D + lane];

    unsigned int run_c = 0xffffffffu;
    float sum = 0.f;
#pragma unroll
    for (int j = 0; j < SEG; ++j) {
        unsigned int c = pk[j] >> 16;  // wave-uniform
        if (c != run_c) {
            if (run_c != 0xffffffffu)
                atomicAdd(&embed_sum[(size_t)run_c * D + lane], sum);
            run_c = c;
            sum = 0.f;
        }
        sum += xv[j];
    }
    atomicAdd(&embed_sum[(size_t)run_c * D + lane], sum);
}

__global__ void ema_embed_kernel(const float* __restrict__ embed_avg,
                                 const float* __restrict__ embed_sum,
                                 const float* __restrict__ smoothed,
                                 float* __restrict__ out) {
    int g = blockIdx.x * blockDim.x + threadIdx.x;  // [0, C_CODES*16)
    int c = g >> 4;
    float4 ea = ((const float4*)embed_avg)[g];
    float4 es = ((const float4*)embed_sum)[g];
    float4 na;
    na.x = ea.x * DECAYF + es.x * OMDF;
    na.y = ea.y * DECAYF + es.y * OMDF;
    na.z = ea.z * DECAYF + es.z * OMDF;
    na.w = ea.w * DECAYF + es.w * OMDF;
    ((float4*)(out + OUT_EAVG))[g] = na;
    float sm = smoothed[c];
    float4 ne;
    ne.x = na.x / sm;
    ne.y = na.y / sm;
    ne.z = na.z / sm;
    ne.w = na.w / sm;
    ((float4*)(out + OUT_EMB))[g] = ne;
}

extern "C" void kernel_launch(void* const* d_in, const int* in_sizes, int n_in,
                              void* d_out, int out_size, void* d_ws, size_t ws_size,
                              hipStream_t stream) {
    const float* x            = (const float*)d_in[0];  // (16,4096,64)
    const float* emb          = (const float*)d_in[1];  // (1,2048,64)
    const float* cluster_size = (const float*)d_in[2];  // (1,2048)
    const float* embed_avg    = (const float*)d_in[3];  // (1,2048,64)
    float* out = (float*)d_out;

    // workspace layout (~3.6 MB; ktop2 offset 16B-aligned)
    float* e2        = (float*)d_ws;                        // 2048
    unsigned int* e2p = (unsigned int*)(e2 + C_CODES);      // 2048
    float* counts    = (float*)(e2p + C_CODES);             // 2048 (zeroed in eprep)
    float* smoothed  = counts + C_CODES;                    // 2048
    int*   cursor    = (int*)(smoothed + C_CODES);          // 2048
    int*   idx       = cursor + C_CODES;                    // 65536
    unsigned int* sorted = (unsigned int*)(idx + N_TOK);    // 65536
    uint4* ktop2     = (uint4*)(sorted + N_TOK);            // 65536*2 uint4 = 2 MB
    float* embed_sum = (float*)(ktop2 + (size_t)N_TOK * 2); // 131072 (zeroed in eprep)
    short* ebk       = (short*)(embed_sum + C_CODES * D);   // 262144 shorts (512 KB)

    eprep_kernel<<<(C_CODES * 8) / 256, 256, 0, stream>>>(emb, ebk, e2, e2p, counts, embed_sum);
    screen_kernel<<<dim3(N_TOK / 128, 2), 256, 0, stream>>>(x, ebk, e2p, ktop2);
    exact_kernel<<<N_TOK / 256, 256, 0, stream>>>(x, emb, e2, ktop2, idx, out, counts);
    prefix_ema_kernel<<<1, 256, 0, stream>>>(counts, cluster_size, out, smoothed, cursor);
    scatter_pos_kernel<<<N_TOK / 256, 256, 0, stream>>>(idx, cursor, sorted);
    seg_sum_kernel<<<(N_TOK / SEG) / 4, 256, 0, stream>>>(x, sorted, embed_sum);
    ema_embed_kernel<<<(C_CODES * 16) / 256, 256, 0, stream>>>(embed_avg, embed_sum,
                                                              smoothed, out);
}

// Round 8
// 249.633 us; speedup vs baseline: 1.5178x; 1.5178x over previous
//
#include <hip/hip_runtime.h>

#define N_TOK 65536
#define D 64
#define C_CODES 2048
#define DECAYF 0.8f
#define OMDF 0.2f
#define EPSF 1e-5f
#define SEG 16          // sorted positions per wave in seg_sum
#define GAP_THR 0.0625f // >> 2x worst-case split-bf16 screen error (~0.008)
#define TCODES 64       // codes per staged LDS tile
#define HT (1024 / TCODES)  // 16 tiles per codebook half

// output layout (floats), concatenated in reference return order
#define OUT_QUANT 0
#define OUT_IND   (N_TOK * D)               // 4194304
#define OUT_EMB   (OUT_IND + N_TOK)         // 4259840
#define OUT_CS    (OUT_EMB + C_CODES * D)   // 4390912
#define OUT_EAVG  (OUT_CS + C_CODES)        // 4392960

typedef short s16x8 __attribute__((ext_vector_type(8)));  // 8 bf16 (4 VGPRs)
typedef float f32x4 __attribute__((ext_vector_type(4)));

__device__ __forceinline__ unsigned short f2bf(float f) {  // RNE float->bf16 bits
    unsigned int u = __float_as_uint(f);
    return (unsigned short)((u + 0x7fffu + ((u >> 16) & 1u)) >> 16);
}
__device__ __forceinline__ float bf2f(unsigned short h) {
    return __uint_as_float(((unsigned int)h) << 16);
}
__device__ __forceinline__ unsigned long long shflx64w(unsigned long long v, int mask, int w) {
    unsigned int lo = (unsigned int)v, hi = (unsigned int)(v >> 32);
    lo = __shfl_xor(lo, mask, w);
    hi = __shfl_xor(hi, mask, w);
    return ((unsigned long long)hi << 32) | lo;
}
__device__ __forceinline__ void gload_lds16(const void* g, void* l) {
    __builtin_amdgcn_global_load_lds(
        (const __attribute__((address_space(1))) void*)g,
        (__attribute__((address_space(3))) void*)l, 16, 0, 0);
}

// Codebook prep: hi/lo bf16 split, PRE-SWIZZLED rows (slot s holds k-chunk
// s^(code&7)) so linear global_load_lds + swizzled ds_read_b128 is
// conflict-free. g<2048 also computes e2 with the VERBATIM validated fmaf
// tree + the bf16-pair e2p. Zeroes counts/embed_sum (no memsets).
__global__ void eprep_kernel(const float* __restrict__ emb, short* __restrict__ ebk,
                             float* __restrict__ e2, unsigned int* __restrict__ e2p,
                             float* __restrict__ counts, float* __restrict__ embed_sum) {
    int g = blockIdx.x * blockDim.x + threadIdx.x;  // [0, C_CODES*8)
    int code = g >> 3, slot = g & 7;
    int kc = slot ^ (code & 7);
    const float4* ep = (const float4*)(emb + (size_t)code * D + kc * 8);
    float4 a = ep[0], b = ep[1];
    float v[8] = {a.x, a.y, a.z, a.w, b.x, b.y, b.z, b.w};
    s16x8 h, l;
#pragma unroll
    for (int j = 0; j < 8; ++j) {
        unsigned short hb = f2bf(v[j]);
        h[j] = (short)hb;
        l[j] = (short)f2bf(v[j] - bf2f(hb));
    }
    *(s16x8*)(ebk + (size_t)code * 128 + slot * 8) = h;
    *(s16x8*)(ebk + (size_t)code * 128 + 64 + slot * 8) = l;

    float4 z = {0.f, 0.f, 0.f, 0.f};
    ((float4*)embed_sum)[g * 2] = z;
    ((float4*)embed_sum)[g * 2 + 1] = z;
    if (g < C_CODES / 4) ((float4*)counts)[g] = z;

    if (g < C_CODES) {  // verbatim e2 tree
        const float4* er = (const float4*)(emb + (size_t)g * D);
        float s0 = 0.f, s1 = 0.f, s2 = 0.f, s3 = 0.f;
#pragma unroll
        for (int i = 0; i < D / 4; ++i) {
            float4 e = er[i];
            s0 = fmaf(e.x, e.x, s0);
            s1 = fmaf(e.y, e.y, s1);
            s2 = fmaf(e.z, e.z, s2);
            s3 = fmaf(e.w, e.w, s3);
        }
        float vv = (s0 + s1) + (s2 + s3);
        e2[g] = vv;
        unsigned short hb = f2bf(vv);
        unsigned short lb = f2bf(vv - bf2f(hb));
        e2p[g] = (unsigned int)hb | ((unsigned int)lb << 16);
    }
}

// MFMA screening over HALF the codebook per block (blockIdx.y). Branchless
// top-3-score / top-2-code tracking via the med3 identities:
//   b3' = med3(b2_old, b3, sc)   (1 op, no cmp)
//   b2' = med3(b1_old, b2, sc)
// 8 VALU/score. Emits per half: uint4 {b1,c1,b2,c2} + float b3.
__global__ __launch_bounds__(256) void screen_kernel(
        const float* __restrict__ x, const short* __restrict__ ebk,
        const unsigned int* __restrict__ e2p, uint4* __restrict__ ktop2,
        float* __restrict__ kb3) {
    __shared__ unsigned int e2pl[1024];                     // 4 KB (this half)
    __shared__ __align__(16) char bstage[2][TCODES * 256];  // 2 x 16 KB

    const int tid = threadIdx.x;
    const int bh = blockIdx.y;  // codebook half (0/1)
    ((uint4*)e2pl)[tid] = ((const uint4*)(e2p + bh * 1024))[tid];

    const int lane = tid & 63;
    const int wave = tid >> 6;
    const int col = lane & 15;   // B col / C col (code within subtile)
    const int krow = lane >> 4;  // k-group

    // A fragments: 2 sets of 16 tokens; split (-2*x) to bf16 hi/lo in-reg.
    s16x8 ah[2][2], al[2][2];
#pragma unroll
    for (int s = 0; s < 2; ++s) {
        int tok = blockIdx.x * 128 + wave * 32 + s * 16 + col;
        const float4* xp = (const float4*)(x + (size_t)tok * D + krow * 8);
        float4 f0 = xp[0], f1 = xp[1], f2 = xp[8], f3 = xp[9];
        float xv[16] = {f0.x, f0.y, f0.z, f0.w, f1.x, f1.y, f1.z, f1.w,
                        f2.x, f2.y, f2.z, f2.w, f3.x, f3.y, f3.z, f3.w};
#pragma unroll
        for (int j = 0; j < 8; ++j) {
            float v0 = -2.0f * xv[j];
            unsigned short h0 = f2bf(v0);
            ah[s][0][j] = (short)h0;
            al[s][0][j] = (short)f2bf(v0 - bf2f(h0));
            float v1 = -2.0f * xv[8 + j];
            unsigned short h1 = f2bf(v1);
            ah[s][1][j] = (short)h1;
            al[s][1][j] = (short)f2bf(v1 - bf2f(h1));
        }
    }

    // constant-A operand for the e2 fold: rows all 1.0 at k-slots 0,1.
    s16x8 aone = {0, 0, 0, 0, 0, 0, 0, 0};
    {
        short o = (krow == 0) ? (short)0x3F80 : (short)0;
        aone[0] = o;
        aone[1] = o;
    }
    const f32x4 zero = {0.f, 0.f, 0.f, 0.f};

    // top-3 scores + top-2 codes, per set per accumulator row
    float b1[2][4], b2[2][4], b3[2][4];
    unsigned int c1[2][4], c2[2][4];
#pragma unroll
    for (int s = 0; s < 2; ++s)
#pragma unroll
        for (int r = 0; r < 4; ++r) {
            b1[s][r] = __builtin_inff();
            b2[s][r] = __builtin_inff();
            b3[s][r] = __builtin_inff();
            c1[s][r] = 0u;
            c2[s][r] = 0u;
        }

    // stage one 64-code tile (16 KB): 4 waves x 4 x global_load_lds(16B)
    auto stage = [&](int b, int t) {
        const char* src = (const char*)ebk + (size_t)(bh * HT + t) * (TCODES * 256)
                          + wave * 4096 + lane * 16;
        char* dst = &bstage[b][wave * 4096];
        gload_lds16(src, dst);
        gload_lds16(src + 1024, dst + 1024);
        gload_lds16(src + 2048, dst + 2048);
        gload_lds16(src + 3072, dst + 3072);
    };

    // one 16-code subtile: 4 ds_read_b128 + e2-fold MFMA + 12 chained MFMA +
    // top-3 update (8 VALU/score)
    auto subtile = [&](const char* lb, int t, int j) {
        const char* base = lb + (j << 12) + (col << 8);
        int off = (krow ^ (col & 7)) << 4;
        s16x8 bh0 = *(const s16x8*)(base + off);
        s16x8 bh1 = *(const s16x8*)(base + (off ^ 64));
        s16x8 bl0 = *(const s16x8*)(base + 128 + off);
        s16x8 bl1 = *(const s16x8*)(base + 128 + (off ^ 64));
        int sloc = t * 4 + j;  // subtile index within half
        unsigned int cg = (unsigned int)(bh * 1024 + sloc * 16 + col);
        unsigned int v = e2pl[sloc * 16 + col];
        v = (krow == 0) ? v : 0u;
        s16x8 be2 = {(short)(v & 0xffffu), (short)(v >> 16), 0, 0, 0, 0, 0, 0};
        f32x4 f = __builtin_amdgcn_mfma_f32_16x16x32_bf16(aone, be2, zero, 0, 0, 0);
#pragma unroll
        for (int s = 0; s < 2; ++s) {
            f32x4 acc = __builtin_amdgcn_mfma_f32_16x16x32_bf16(ah[s][1], bh1, f, 0, 0, 0);
            acc = __builtin_amdgcn_mfma_f32_16x16x32_bf16(ah[s][0], bh0, acc, 0, 0, 0);
            acc = __builtin_amdgcn_mfma_f32_16x16x32_bf16(al[s][1], bh1, acc, 0, 0, 0);
            acc = __builtin_amdgcn_mfma_f32_16x16x32_bf16(al[s][0], bh0, acc, 0, 0, 0);
            acc = __builtin_amdgcn_mfma_f32_16x16x32_bf16(ah[s][1], bl1, acc, 0, 0, 0);
            acc = __builtin_amdgcn_mfma_f32_16x16x32_bf16(ah[s][0], bl0, acc, 0, 0, 0);
#pragma unroll
            for (int r = 0; r < 4; ++r) {
                float sc = acc[r];
                bool l1 = sc < b1[s][r];
                bool l2 = sc < b2[s][r];
                b3[s][r] = __builtin_amdgcn_fmed3f(b2[s][r], b3[s][r], sc);  // old b2
                b2[s][r] = __builtin_amdgcn_fmed3f(b1[s][r], b2[s][r], sc);  // old b1
                unsigned int tc = l1 ? c1[s][r] : cg;
                c2[s][r] = l2 ? tc : c2[s][r];
                b1[s][r] = fminf(b1[s][r], sc);
                c1[s][r] = l1 ? cg : c1[s][r];
            }
        }
    };

    stage(0, 0);
    __syncthreads();  // drains staging + e2pl init

    for (int t = 0; t < HT; ++t) {
        if (t + 1 < HT) stage((t + 1) & 1, t + 1);
        const char* lb = bstage[t & 1];
        subtile(lb, t, 0);
        subtile(lb, t, 1);
        subtile(lb, t, 2);
        subtile(lb, t, 3);
        __syncthreads();
    }

    // cross-lane (16 cols) top-3 merge (codes for top-2), then emit
#pragma unroll
    for (int s = 0; s < 2; ++s)
#pragma unroll
        for (int r = 0; r < 4; ++r) {
            float B1 = b1[s][r], B2 = b2[s][r], B3 = b3[s][r];
            unsigned int C1 = c1[s][r], C2 = c2[s][r];
#pragma unroll
            for (int mk = 1; mk < 16; mk <<= 1) {
                float o1 = __shfl_xor(B1, mk, 16);
                float o2 = __shfl_xor(B2, mk, 16);
                float o3 = __shfl_xor(B3, mk, 16);
                unsigned int oc1 = (unsigned int)__shfl_xor((int)C1, mk, 16);
                unsigned int oc2 = (unsigned int)__shfl_xor((int)C2, mk, 16);
                bool ta = B1 <= o1;
                float x1v = ta ? o1 : B1;
                unsigned int xc = ta ? oc1 : C1;
                float nm1 = ta ? B1 : o1;
                unsigned int nc1 = ta ? C1 : oc1;
                bool tb = B2 <= o2;
                float y1v = tb ? B2 : o2;
                unsigned int yc = tb ? C2 : oc2;
                bool tc = x1v <= y1v;
                float nm2 = tc ? x1v : y1v;
                unsigned int nc2 = tc ? xc : yc;
                float nm3 = fminf(fmaxf(x1v, y1v), fminf(B3, o3));
                B1 = nm1; C1 = nc1; B2 = nm2; C2 = nc2; B3 = nm3;
            }
            if (col == 0) {
                int tok = blockIdx.x * 128 + wave * 32 + s * 16 + krow * 4 + r;
                uint4 o;
                o.x = __float_as_uint(B1);
                o.y = C1;
                o.z = __float_as_uint(B2);
                o.w = C2;
                ktop2[(size_t)tok * 2 + bh] = o;
                kb3[(size_t)tok * 2 + bh] = B3;
            }
        }
}

// Merge both halves' top-3: uniq (gap12>THR) -> provable argmin; pairf
// (gap13>THR) -> exact f32 rescore of {c1,c2} (VERBATIM tree, key-min ties ->
// smaller c); else rare WAVE-COOPERATIVE full scan. Fused gather + histogram.
__global__ __launch_bounds__(256) void exact_kernel(
        const float* __restrict__ x, const float* __restrict__ emb,
        const float* __restrict__ e2, const uint4* __restrict__ ktop2,
        const float* __restrict__ kb3,
        int* __restrict__ idx, float* __restrict__ out,
        float* __restrict__ counts) {
    __shared__ float lcount[C_CODES];
    for (int i = threadIdx.x; i < C_CODES; i += blockDim.x) lcount[i] = 0.0f;
    __syncthreads();
    int n = blockIdx.x * blockDim.x + threadIdx.x;
    int lane = threadIdx.x & 63;

    uint4 A = ktop2[(size_t)n * 2];
    uint4 B = ktop2[(size_t)n * 2 + 1];
    float a3 = kb3[(size_t)n * 2], b3v = kb3[(size_t)n * 2 + 1];
    float a1 = __uint_as_float(A.x), a2 = __uint_as_float(A.z);
    float b1f = __uint_as_float(B.x), b2f = __uint_as_float(B.z);

    // merge two sorted triples -> m1,m2 (with codes) + m3 (value)
    bool ta = a1 <= b1f;
    float m1 = ta ? a1 : b1f;
    int cm1 = (int)(ta ? A.y : B.y);
    float x1v = ta ? b1f : a1;
    int xc = (int)(ta ? B.y : A.y);
    bool tb = a2 <= b2f;
    float y1v = tb ? a2 : b2f;
    int yc = (int)(tb ? A.w : B.w);
    bool tc = x1v <= y1v;
    float m2 = tc ? x1v : y1v;
    int cm2 = tc ? xc : yc;
    float m3 = fminf(fmaxf(x1v, y1v), fminf(a3, b3v));

    int c = cm1;
    bool uniq = (m2 - m1 > GAP_THR);
    bool pairf = !uniq && (m3 - m1 > GAP_THR);
    bool fullf = !uniq && !pairf;

    if (pairf) {  // exact rescore of the two near-tied codes, chunked (no spill)
        int ca = cm1, cb = cm2;
        float xs[4] = {0.f, 0.f, 0.f, 0.f};
        float da[4] = {0.f, 0.f, 0.f, 0.f};
        float db[4] = {0.f, 0.f, 0.f, 0.f};
        for (int q = 0; q < 4; ++q) {
            const float4* xq = (const float4*)(x + (size_t)n * D + q * 16);
            const float4* ea = (const float4*)(emb + (size_t)ca * D + q * 16);
            const float4* eb = (const float4*)(emb + (size_t)cb * D + q * 16);
#pragma unroll
            for (int j = 0; j < 4; ++j) {
                float4 xv = xq[j], av = ea[j], bv = eb[j];
                xs[0] = fmaf(xv.x, xv.x, xs[0]);
                xs[1] = fmaf(xv.y, xv.y, xs[1]);
                xs[2] = fmaf(xv.z, xv.z, xs[2]);
                xs[3] = fmaf(xv.w, xv.w, xs[3]);
                da[0] = fmaf(xv.x, av.x, da[0]);
                da[1] = fmaf(xv.y, av.y, da[1]);
                da[2] = fmaf(xv.z, av.z, da[2]);
                da[3] = fmaf(xv.w, av.w, da[3]);
                db[0] = fmaf(xv.x, bv.x, db[0]);
                db[1] = fmaf(xv.y, bv.y, db[1]);
                db[2] = fmaf(xv.z, bv.z, db[2]);
                db[3] = fmaf(xv.w, bv.w, db[3]);
            }
        }
        float x2 = (xs[0] + xs[1]) + (xs[2] + xs[3]);
        float dota = (da[0] + da[1]) + (da[2] + da[3]);
        float dA = fmaxf(x2 + e2[ca] - 2.0f * dota, 0.0f);
        float dotb = (db[0] + db[1]) + (db[2] + db[3]);
        float dB = fmaxf(x2 + e2[cb] - 2.0f * dotb, 0.0f);
        unsigned long long ka = ((unsigned long long)__float_as_uint(dA) << 32) | (unsigned int)ca;
        unsigned long long kb = ((unsigned long long)__float_as_uint(dB) << 32) | (unsigned int)cb;
        c = (int)((ka < kb ? ka : kb) & 0xffffffffull);
    }

    // rare cooperative exact scan (chunked x reloads: no big live ranges)
    unsigned long long bal = __ballot(fullf);
    while (bal) {
        int src = (int)__ffsll((long long)bal) - 1;
        bal &= bal - 1;
        int tn = (n & ~63) + src;
        float xs[4] = {0.f, 0.f, 0.f, 0.f};
        for (int q = 0; q < 4; ++q) {
            const float4* xq = (const float4*)(x + (size_t)tn * D + q * 16);
#pragma unroll
            for (int j = 0; j < 4; ++j) {
                float4 xv = xq[j];
                xs[0] = fmaf(xv.x, xv.x, xs[0]);
                xs[1] = fmaf(xv.y, xv.y, xs[1]);
                xs[2] = fmaf(xv.z, xv.z, xs[2]);
                xs[3] = fmaf(xv.w, xv.w, xs[3]);
            }
        }
        float tx2 = (xs[0] + xs[1]) + (xs[2] + xs[3]);
        unsigned long long kbest = ~0ull;
        for (int cc = lane; cc < C_CODES; cc += 64) {
            float d0 = 0.f, d1 = 0.f, d2 = 0.f, d3 = 0.f;
            for (int q = 0; q < 4; ++q) {
                const float4* xq = (const float4*)(x + (size_t)tn * D + q * 16);
                const float4* er = (const float4*)(emb + (size_t)cc * D + q * 16);
#pragma unroll
                for (int j = 0; j < 4; ++j) {
                    float4 xv = xq[j], ev = er[j];
                    d0 = fmaf(xv.x, ev.x, d0);
                    d1 = fmaf(xv.y, ev.y, d1);
                    d2 = fmaf(xv.z, ev.z, d2);
                    d3 = fmaf(xv.w, ev.w, d3);
                }
            }
            float dot = (d0 + d1) + (d2 + d3);
            float dist2 = fmaxf(tx2 + e2[cc] - 2.0f * dot, 0.0f);
            unsigned long long key =
                ((unsigned long long)__float_as_uint(dist2) << 32) | (unsigned int)cc;
            kbest = key < kbest ? key : kbest;
        }
#pragma unroll
        for (int mk = 1; mk < 64; mk <<= 1) {
            unsigned long long o = shflx64w(kbest, mk, 64);
            kbest = o < kbest ? o : kbest;
        }
        if (lane == src) c = (int)(kbest & 0xffffffffull);
    }

    idx[n] = c;
    out[OUT_IND + n] = (float)c;
    atomicAdd(&lcount[c], 1.0f);

    // fused quantize gather: copy code row (codebook is L2-resident)
    {
        const float4* er = (const float4*)(emb + (size_t)c * D);
        float4* qo = (float4*)(out + OUT_QUANT) + (size_t)n * 16;
#pragma unroll
        for (int q = 0; q < 16; ++q) qo[q] = er[q];
    }

    __syncthreads();
    for (int i = threadIdx.x; i < C_CODES; i += blockDim.x) {
        float vv = lcount[i];
        if (vv != 0.0f) atomicAdd(&counts[i], vv);
    }
}

// Single block: EMA cluster-size + laplace smoothing + exclusive prefix sum.
__global__ void prefix_ema_kernel(const float* __restrict__ counts,
                                  const float* __restrict__ cluster_size,
                                  float* __restrict__ out,
                                  float* __restrict__ smoothed,
                                  int* __restrict__ cursor) {
    __shared__ float scan[256];
    __shared__ float red[256];
    int t = threadIdx.x;
    int base = t * 8;
    float cnt[8], ncs[8];
    float csum = 0.f, nsum = 0.f;
#pragma unroll
    for (int j = 0; j < 8; ++j) {
        cnt[j] = counts[base + j];
        csum += cnt[j];
        ncs[j] = cluster_size[base + j] * DECAYF + cnt[j] * OMDF;
        nsum += ncs[j];
        out[OUT_CS + base + j] = ncs[j];
    }
    scan[t] = csum;
    red[t] = nsum;
    __syncthreads();
    for (int s = 1; s < 256; s <<= 1) {
        float v = scan[t];
        float w = (t >= s) ? scan[t - s] : 0.f;
        __syncthreads();
        scan[t] = v + w;
        __syncthreads();
    }
    for (int s = 128; s > 0; s >>= 1) {
        if (t < s) red[t] += red[t + s];
        __syncthreads();
    }
    float tot = red[0];
    float run = (t == 0) ? 0.f : scan[t - 1];
#pragma unroll
    for (int j = 0; j < 8; ++j) {
        cursor[base + j] = (int)run;  // counts are small ints in float: exact
        run += cnt[j];
        smoothed[base + j] = (ncs[j] + EPSF) / (tot + (float)C_CODES * EPSF) * tot;
    }
}

// counting-sort position scatter; entry packs (code<<16 | token).
__global__ void scatter_pos_kernel(const int* __restrict__ idx,
                                   int* __restrict__ cursor,
                                   unsigned int* __restrict__ sorted) {
    int n = blockIdx.x * blockDim.x + threadIdx.x;
    int c = idx[n];
    int pos = atomicAdd(&cursor[c], 1);
    sorted[pos] = ((unsigned int)c << 16) | (unsigned int)n;
}

// Segmented sum over sorted positions: one 64-lane atomicAdd per run boundary.
__global__ __launch_bounds__(256) void seg_sum_kernel(
        const float* __restrict__ x, const unsigned int* __restrict__ sorted,
        float* __restrict__ embed_sum) {
    int lane = threadIdx.x & 63;
    int q = blockIdx.x * 4 + (threadIdx.x >> 6);  // wave id
    int p0 = q * SEG;

    unsigned int mine = (lane < SEG) ? sorted[p0 + lane] : 0u;
    unsigned int pk[SEG];
#pragma unroll
    for (int j = 0; j < SEG; ++j) pk[j] = __shfl(mine, j, 64);

    float xv[SEG];
#pragma unroll
    for (int j = 0; j < SEG; ++j)
        xv[j] = x[(size_t)(pk[j] & 0xffffu) * D + lane];

    unsigned int run_c = 0xffffffffu;
    float sum = 0.f;
#pragma unroll
    for (int j = 0; j < SEG; ++j) {
        unsigned int c = pk[j] >> 16;  // wave-uniform
        if (c != run_c) {
            if (run_c != 0xffffffffu)
                atomicAdd(&embed_sum[(size_t)run_c * D + lane], sum);
            run_c = c;
            sum = 0.f;
        }
        sum += xv[j];
    }
    atomicAdd(&embed_sum[(size_t)run_c * D + lane], sum);
}

__global__ void ema_embed_kernel(const float* __restrict__ embed_avg,
                                 const float* __restrict__ embed_sum,
                                 const float* __restrict__ smoothed,
                                 float* __restrict__ out) {
    int g = blockIdx.x * blockDim.x + threadIdx.x;  // [0, C_CODES*16)
    int c = g >> 4;
    float4 ea = ((const float4*)embed_avg)[g];
    float4 es = ((const float4*)embed_sum)[g];
    float4 na;
    na.x = ea.x * DECAYF + es.x * OMDF;
    na.y = ea.y * DECAYF + es.y * OMDF;
    na.z = ea.z * DECAYF + es.z * OMDF;
    na.w = ea.w * DECAYF + es.w * OMDF;
    ((float4*)(out + OUT_EAVG))[g] = na;
    float sm = smoothed[c];
    float4 ne;
    ne.x = na.x / sm;
    ne.y = na.y / sm;
    ne.z = na.z / sm;
    ne.w = na.w / sm;
    ((float4*)(out + OUT_EMB))[g] = ne;
}

extern "C" void kernel_launch(void* const* d_in, const int* in_sizes, int n_in,
                              void* d_out, int out_size, void* d_ws, size_t ws_size,
                              hipStream_t stream) {
    const float* x            = (const float*)d_in[0];  // (16,4096,64)
    const float* emb          = (const float*)d_in[1];  // (1,2048,64)
    const float* cluster_size = (const float*)d_in[2];  // (1,2048)
    const float* embed_avg    = (const float*)d_in[3];  // (1,2048,64)
    float* out = (float*)d_out;

    // workspace layout (~4.2 MB; ktop2 offset 16B-aligned)
    float* e2        = (float*)d_ws;                        // 2048
    unsigned int* e2p = (unsigned int*)(e2 + C_CODES);      // 2048
    float* counts    = (float*)(e2p + C_CODES);             // 2048 (zeroed in eprep)
    float* smoothed  = counts + C_CODES;                    // 2048
    int*   cursor    = (int*)(smoothed + C_CODES);          // 2048
    int*   idx       = cursor + C_CODES;                    // 65536
    unsigned int* sorted = (unsigned int*)(idx + N_TOK);    // 65536
    uint4* ktop2     = (uint4*)(sorted + N_TOK);            // 65536*2 uint4 = 2 MB
    float* kb3       = (float*)(ktop2 + (size_t)N_TOK * 2); // 65536*2 = 512 KB
    float* embed_sum = kb3 + (size_t)N_TOK * 2;             // 131072 (zeroed in eprep)
    short* ebk       = (short*)(embed_sum + C_CODES * D);   // 262144 shorts (512 KB)

    eprep_kernel<<<(C_CODES * 8) / 256, 256, 0, stream>>>(emb, ebk, e2, e2p, counts, embed_sum);
    screen_kernel<<<dim3(N_TOK / 128, 2), 256, 0, stream>>>(x, ebk, e2p, ktop2, kb3);
    exact_kernel<<<N_TOK / 256, 256, 0, stream>>>(x, emb, e2, ktop2, kb3, idx, out, counts);
    prefix_ema_kernel<<<1, 256, 0, stream>>>(counts, cluster_size, out, smoothed, cursor);
    scatter_pos_kernel<<<N_TOK / 256, 256, 0, stream>>>(idx, cursor, sorted);
    seg_sum_kernel<<<(N_TOK / SEG) / 4, 256, 0, stream>>>(x, sorted, embed_sum);
    ema_embed_kernel<<<(C_CODES * 16) / 256, 256, 0, stream>>>(embed_avg, embed_sum,
                                                              smoothed, out);
}